// Round 18
// baseline (101.824 us; speedup 1.0000x reference)
//
#include <hip/hip_runtime.h>

// Chamfer via MFMA half-distance matrix, v14: GUARANTEED umin + max TLP.
// R17 post-mortem: halving MFMA demand (MfmaUtil 28->14%) did NOT move the
// 46us wall => additive-demand model refuted; the binding term is VALU
// busy-time, pinned at ~19.7us/SIMD since R9 = ~4-5x the static min-op
// count. Suspects: (a) u32 ternary min not folding to v_min_u32/v_min3_u32
// (cmp+cndmask = 4x), (b) AGPR round-trips (VGPR=64 signature). Occupancy
// 26% (~2 waves/SIMD) hides none of it.
// R18: (1) __builtin_elementwise_min everywhere -> llvm.umin -> guaranteed
// v_min_u32/min3 folding; (2) drop in-loop shfl_xor(32): per-half col-min
// LDS sht[2][DBR] (distinct banks per half, 2-way same-bank = free), halves
// merged once at flush; (3) DSPLIT=8 -> 2048 blocks = 8 blocks/CU for up
// to 8 waves/SIMD. DECISIVE TELL: VALU busy-time (VALUBusy x dur) <= 12us
// => fusion theory right; stays ~19-20us => inflation is AGPR traffic,
// irreducible at HIP source, practical floor reached.
//
// Math (R16/R17 verified, absmax 0.0): h+1 = 0.5|q|^2+0.5|t|^2-q.t+1 via
// K=16 mfma_f32_32x32x16_bf16, bf16 hi/lo split, bias slot 13 (A=1,B=1):
//   A(q): half0 [xh xh xl yh yh yl zh zh]  half1 [zl qh ql 1 1 1 0 0]
//   B(t): half0 [nxh nxl nxh nyh nyl nyh nzh nzl] half1 [nzh 1 1 hh hl 1 0 0]
// h+1 >= 0.99 > 0 -> u32 bit order == float order. C layout (m74/m101):
// col=lane&31 (db pt), row=(reg&3)+8*(reg>>2)+4*half.

typedef float f32x16 __attribute__((ext_vector_type(16)));
typedef short bf16x8 __attribute__((ext_vector_type(8)));

constexpr int BATCH  = 8;
constexpr int NPTS   = 8192;
constexpr int BLOCK  = 256;            // 4 waves
constexpr int QTILE  = 256;            // queries per block (64 per wave)
constexpr int NAF    = 2;              // A-frags per wave
constexpr int QB     = NPTS / QTILE;   // 32 query blocks
constexpr int DSPLIT = 8;              // db split
constexpr int DBR    = NPTS / DSPLIT;  // 1024 db points per block
constexpr int NT     = DBR / 32;       // 32 B-tiles of 32 points
constexpr int NBLK   = QB * BATCH * DSPLIT;   // 2048

// workspace: fragT [B][NPTS][2] uint4 (2MB) | mins [2][B][NPTS] u32 (512KB)
constexpr size_t FRAG_N = (size_t)BATCH * NPTS * 2;   // uint4s
constexpr size_t SM_N   = (size_t)BATCH * NPTS;       // u32 per direction

static __device__ __forceinline__ unsigned umin2(unsigned a, unsigned b) {
    return __builtin_elementwise_min(a, b);          // llvm.umin -> v_min_u32
}
static __device__ __forceinline__ unsigned umin3(unsigned a, unsigned b, unsigned c) {
    return umin2(a, umin2(b, c));                    // folds to v_min3_u32
}
static __device__ __forceinline__ unsigned u(float f) { return __float_as_uint(f); }

// min over the 16 fp32 regs of one MFMA result, u32 domain (8 min3-class ops)
static __device__ __forceinline__ unsigned tree16u(const f32x16& a) {
    unsigned m = umin3(u(a[0]), u(a[1]), u(a[2]));
    m = umin3(m, u(a[3]),  u(a[4]));  m = umin3(m, u(a[5]),  u(a[6]));
    m = umin3(m, u(a[7]),  u(a[8]));  m = umin3(m, u(a[9]),  u(a[10]));
    m = umin3(m, u(a[11]), u(a[12])); m = umin3(m, u(a[13]), u(a[14]));
    return umin2(m, u(a[15]));
}

static __device__ __forceinline__ unsigned short bf16h(float f) {
    unsigned int v = __float_as_uint(f);
    v += 0x7fffu + ((v >> 16) & 1u);           // RNE
    return (unsigned short)(v >> 16);
}
static __device__ __forceinline__ float bf16tof(unsigned short h) {
    return __uint_as_float(((unsigned int)h) << 16);
}
static __device__ __forceinline__ unsigned int pack2(unsigned short a, unsigned short b) {
    return (unsigned int)a | ((unsigned int)b << 16);
}

// ---- prep: tgt -> B-fragments; init mins; zero out ----
__global__ __launch_bounds__(BLOCK) void chamfer_prep(
    const float* __restrict__ tgt, uint4* __restrict__ fragT,
    unsigned int* __restrict__ mins, float* __restrict__ out)
{
    const int i = blockIdx.x * BLOCK + threadIdx.x;   // [0, B*NPTS)
    const unsigned short one = bf16h(1.0f);
    const float* tp = tgt + (size_t)i * 3;
    float px = tp[0], py = tp[1], pz = tp[2];
    float nx = -px, ny = -py, nz = -pz;
    float ht = 0.5f * fmaf(px, px, fmaf(py, py, pz * pz));
    unsigned short nxh = bf16h(nx), nxl = bf16h(nx - bf16tof(nxh));
    unsigned short nyh = bf16h(ny), nyl = bf16h(ny - bf16tof(nyh));
    unsigned short nzh = bf16h(nz), nzl = bf16h(nz - bf16tof(nzh));
    unsigned short hh = bf16h(ht),  hl = bf16h(ht - bf16tof(hh));
    fragT[2 * i + 0] = make_uint4(pack2(nxh, nxl), pack2(nxh, nyh),
                                  pack2(nyl, nyh), pack2(nzh, nzl));
    fragT[2 * i + 1] = make_uint4(pack2(nzh, one), pack2(one, hh),
                                  pack2(hl, one), 0u);   // slot 13 = 1 (bias)
    mins[i]        = 0x7f7f7f7fu;
    mins[SM_N + i] = 0x7f7f7f7fu;
    if (i < BATCH) out[i] = 0.0f;
}

__global__ __launch_bounds__(BLOCK, 2) void chamfer_nn(
    const float* __restrict__ src, const uint4* __restrict__ fragT,
    unsigned int* __restrict__ mins)
{
    __shared__ unsigned sht[2][DBR];   // per-half col-mins (biased u32), 8KB

    const int tid  = threadIdx.x;
    const int lane = tid & 63;
    const int w    = tid >> 6;
    const int half = lane >> 5;
    const int l31  = lane & 31;

    // ---- XCD-panel swizzle (bijective on [0,2048)) ----
    // panel = (b,ds) in [0,64); its 32 qb-siblings share lin&7 -> same XCD
    // -> 32KB fragment panel L2-resident (validated R10-R17).
    const int lin  = blockIdx.x;
    const int rest = lin >> 3;                        // [0,256)
    const int qb   = rest & 31;                       // [0,32)
    const int p    = ((rest >> 5) << 3) | (lin & 7);  // panel [0,64)
    const int b    = p & 7;
    const int ds   = p >> 3;                          // [0,8)

    // init col-min slots; one barrier before any wave's ds_min
    for (int j = tid; j < 2 * DBR; j += BLOCK) sht[0][j] = 0x7f7f7f7fu;

    // ---- build NAF A-fragments from src ----
    const unsigned short one = bf16h(1.0f);
    bf16x8 af[NAF];
#pragma unroll
    for (int g = 0; g < NAF; g++) {
        const int q = qb * QTILE + w * (32 * NAF) + g * 32 + l31;
        const float* qp = src + ((size_t)b * NPTS + q) * 3;
        float qx = qp[0], qy = qp[1], qz = qp[2];
        float hq = 0.5f * fmaf(qx, qx, fmaf(qy, qy, qz * qz));
        unsigned short xh = bf16h(qx), xl = bf16h(qx - bf16tof(xh));
        unsigned short yh = bf16h(qy), yl = bf16h(qy - bf16tof(yh));
        unsigned short zh = bf16h(qz), zl = bf16h(qz - bf16tof(zh));
        unsigned short qh = bf16h(hq), ql = bf16h(hq - bf16tof(qh));
        bf16x8 a;
        if (half == 0) {
            a[0] = (short)xh; a[1] = (short)xh; a[2] = (short)xl;
            a[3] = (short)yh; a[4] = (short)yh; a[5] = (short)yl;
            a[6] = (short)zh; a[7] = (short)zh;
        } else {
            a[0] = (short)zl; a[1] = (short)qh; a[2] = (short)ql;
            a[3] = (short)one; a[4] = (short)one;
            a[5] = (short)one;  // slot 13: pairs B's 1 -> +1.0 bias
            a[6] = 0; a[7] = 0;
        }
        af[g] = a;
    }

    unsigned rmn0[16], rmn1[16];
#pragma unroll
    for (int r = 0; r < 16; r++) { rmn0[r] = 0x7f7f7f7fu; rmn1[r] = 0x7f7f7f7fu; }
    const f32x16 zz = {};

    // per-lane B pointer (element 64*t + 2*l31 + half); coalesced, L2-hot.
    const uint4* gp = fragT + ((size_t)b * NPTS + (size_t)ds * DBR) * 2
                            + 2 * l31 + half;

    __syncthreads();   // sht init visible before any ds_min

    // register prefetch, 1-iteration distance (T14)
    uint4 c0 = gp[0], c1 = gp[64];
    for (int t = 0; t < NT; t += 2) {
        bf16x8 b0 = __builtin_bit_cast(bf16x8, c0);
        bf16x8 b1 = __builtin_bit_cast(bf16x8, c1);
        if (t + 2 < NT) {                   // issue next pair early
            c0 = gp[64 * (t + 2)];
            c1 = gp[64 * (t + 3)];
        }
        // ONE MFMA per unique tile x A-group (single-pass, R17-validated)
        f32x16 a00 = __builtin_amdgcn_mfma_f32_32x32x16_bf16(af[0], b0, zz, 0, 0, 0);
        f32x16 a01 = __builtin_amdgcn_mfma_f32_32x32x16_bf16(af[0], b1, zz, 0, 0, 0);
        f32x16 a10 = __builtin_amdgcn_mfma_f32_32x32x16_bf16(af[1], b0, zz, 0, 0, 0);
        f32x16 a11 = __builtin_amdgcn_mfma_f32_32x32x16_bf16(af[1], b1, zz, 0, 0, 0);
        // s2t: row-min accumulate (min over db points), u32 domain
#pragma unroll
        for (int r = 0; r < 16; r++) {
            rmn0[r] = umin3(rmn0[r], u(a00[r]), u(a01[r]));
            rmn1[r] = umin3(rmn1[r], u(a10[r]), u(a11[r]));
        }
        // t2s: per-half col-min (no in-loop shfl; halves merged at flush).
        // Lanes 0-31 hit sht[0] banks 0-31, lanes 32-63 sht[1] banks 0-31:
        // 2 lanes/bank = free (m136).
        unsigned t0 = umin2(tree16u(a00), tree16u(a10));   // tile t
        unsigned t1 = umin2(tree16u(a01), tree16u(a11));   // tile t+1
        atomicMin(&sht[half][t * 32 + l31],       t0);
        atomicMin(&sht[half][(t + 1) * 32 + l31], t1);
    }

    // ---- s2t epilogue: fold cols 32->1 in-wave, global atomicMin ----
    unsigned int* M0 = mins + (size_t)b * NPTS;
    const int qbase = qb * QTILE + w * (32 * NAF);
#pragma unroll
    for (int r = 0; r < 16; r++) {
        unsigned a = rmn0[r], bv = rmn1[r];
#pragma unroll
        for (int off = 16; off > 0; off >>= 1) {
            a  = umin2(a,  (unsigned)__shfl_xor((int)a,  off, 64));
            bv = umin2(bv, (unsigned)__shfl_xor((int)bv, off, 64));
        }
        if (l31 == 0) {   // lanes 0 (half0 row) and 32 (half1 row)
            const int row = (r & 3) + 8 * (r >> 2) + 4 * half;
            atomicMin(&M0[qbase + row],      a);
            atomicMin(&M0[qbase + 32 + row], bv);
        }
    }

    // ---- t2s epilogue: merge halves, one global flush per block ----
    __syncthreads();   // all waves' ds_min complete
    unsigned int* M1 = mins + SM_N + (size_t)b * NPTS + (size_t)ds * DBR;
    for (int j = tid; j < DBR; j += BLOCK)
        atomicMin(&M1[j], umin2(sht[0][j], sht[1][j]));
}

// ---- final: un-bias, clamp, sum mins[2][B][NPTS], atomicAdd into out ----
__global__ __launch_bounds__(BLOCK) void chamfer_final(
    const unsigned int* __restrict__ mins, float* __restrict__ out)
{
    const int seg = blockIdx.x;   // 4 segments of 2048
    const int b   = blockIdx.y;
    const int tid = threadIdx.x;
    float acc = 0.0f;
#pragma unroll
    for (int k = 0; k < 8; k++) {
        const size_t i = (size_t)b * NPTS + seg * 2048 + k * BLOCK + tid;
        acc += fmaxf(__uint_as_float(mins[i]) - 1.0f, 0.0f)
             + fmaxf(__uint_as_float(mins[SM_N + i]) - 1.0f, 0.0f);
    }
    for (int off = 32; off > 0; off >>= 1) acc += __shfl_down(acc, off, 64);
    __shared__ float wsum[4];
    if ((tid & 63) == 0) wsum[tid >> 6] = acc;
    __syncthreads();
    if (tid == 0)   // stored values are (d/2 + 1): d = 2*(v-1)
        atomicAdd(&out[b],
                  (wsum[0] + wsum[1] + wsum[2] + wsum[3]) * (2.0f / (float)NPTS));
}

extern "C" void kernel_launch(void* const* d_in, const int* in_sizes, int n_in,
                              void* d_out, int out_size, void* d_ws, size_t ws_size,
                              hipStream_t stream) {
    const float* src = (const float*)d_in[0];  // [B, N, 3]
    const float* tgt = (const float*)d_in[1];  // [B, M, 3]
    float* out = (float*)d_out;                // [B]

    uint4* fragT        = (uint4*)d_ws;                     // 2 MB
    unsigned int* mins  = (unsigned int*)(fragT + FRAG_N);  // 512 KB

    chamfer_prep<<<BATCH * NPTS / BLOCK, BLOCK, 0, stream>>>(
        tgt, fragT, mins, out);
    chamfer_nn<<<NBLK, BLOCK, 0, stream>>>(src, fragT, mins);
    chamfer_final<<<dim3(4, BATCH), BLOCK, 0, stream>>>(mins, out);
}

// Round 20
// 94.326 us; speedup vs baseline: 1.0795x; 1.0795x over previous
//
#include <hip/hip_runtime.h>

// Chamfer via MFMA half-distance matrix, v15: 8-WAVE BLOCKS.
// (R19 resubmission -- the R19 bench died in the container broker, not in
// the kernel; the occupancy hypothesis is still untested.)
// R18 post-mortem: guaranteed-umin was null (VALU busy-time invariant at
// ~20-23us/SIMD since R9) -- min-fusion refuted. The series' occupancy
// pattern is the remaining explanation: blocks->occupancy = 512->18%,
// 1024->23-26%, 2048->31-48%, sub-linear, saturating ~3 blocks/CU even
// with ZERO LDS (R13). With 256-thread blocks that caps ~2.5-3 waves/SIMD;
// at that concurrency the MFMA-blocked time + ~20us VALU + load waits
// cannot overlap -> the 46-50us wall with both pipes <45% busy.
// R20: more waves PER BLOCK -- BLOCK=512 (8 waves), same per-wave work
// (64 queries x DBR db points), DSPLIT=8, 1024 blocks. At the observed
// 2-3 blocks/CU cap -> 16-24 waves/CU = 2-3x concurrency. Single-variable
// vs R18. TELL: OccupancyPercent >= 50. If occupancy rises but dur stays
// >= 44us, VALU issue-rate is the true floor -> practical roofline.
//
// Math (R16-R18 verified, absmax 0.0): h+1 = 0.5|q|^2+0.5|t|^2-q.t+1 via
// K=16 mfma_f32_32x32x16_bf16, bf16 hi/lo split, bias slot 13 (A=1,B=1):
//   A(q): half0 [xh xh xl yh yh yl zh zh]  half1 [zl qh ql 1 1 1 0 0]
//   B(t): half0 [nxh nxl nxh nyh nyl nyh nzh nzl] half1 [nzh 1 1 hh hl 1 0 0]
// h+1 >= 0.99 > 0 -> u32 bit order == float order. C layout (m74/m101):
// col=lane&31 (db pt), row=(reg&3)+8*(reg>>2)+4*half.

typedef float f32x16 __attribute__((ext_vector_type(16)));
typedef short bf16x8 __attribute__((ext_vector_type(8)));

constexpr int BATCH  = 8;
constexpr int NPTS   = 8192;
constexpr int BLOCK  = 512;            // 8 waves per block
constexpr int QTILE  = 512;            // queries per block (64 per wave)
constexpr int NAF    = 2;              // A-frags per wave
constexpr int QB     = NPTS / QTILE;   // 16 query blocks
constexpr int DSPLIT = 8;              // db split
constexpr int DBR    = NPTS / DSPLIT;  // 1024 db points per block
constexpr int NT     = DBR / 32;       // 32 B-tiles of 32 points
constexpr int NBLK   = QB * BATCH * DSPLIT;   // 1024
constexpr int BLK_P  = 256;            // prep/final block size

// workspace: fragT [B][NPTS][2] uint4 (2MB) | mins [2][B][NPTS] u32 (512KB)
constexpr size_t FRAG_N = (size_t)BATCH * NPTS * 2;   // uint4s
constexpr size_t SM_N   = (size_t)BATCH * NPTS;       // u32 per direction

static __device__ __forceinline__ unsigned umin2(unsigned a, unsigned b) {
    return __builtin_elementwise_min(a, b);          // v_min_u32
}
static __device__ __forceinline__ unsigned umin3(unsigned a, unsigned b, unsigned c) {
    return umin2(a, umin2(b, c));                    // v_min3_u32
}
static __device__ __forceinline__ unsigned u(float f) { return __float_as_uint(f); }

// min over the 16 fp32 regs of one MFMA result, u32 domain
static __device__ __forceinline__ unsigned tree16u(const f32x16& a) {
    unsigned m = umin3(u(a[0]), u(a[1]), u(a[2]));
    m = umin3(m, u(a[3]),  u(a[4]));  m = umin3(m, u(a[5]),  u(a[6]));
    m = umin3(m, u(a[7]),  u(a[8]));  m = umin3(m, u(a[9]),  u(a[10]));
    m = umin3(m, u(a[11]), u(a[12])); m = umin3(m, u(a[13]), u(a[14]));
    return umin2(m, u(a[15]));
}

static __device__ __forceinline__ unsigned short bf16h(float f) {
    unsigned int v = __float_as_uint(f);
    v += 0x7fffu + ((v >> 16) & 1u);           // RNE
    return (unsigned short)(v >> 16);
}
static __device__ __forceinline__ float bf16tof(unsigned short h) {
    return __uint_as_float(((unsigned int)h) << 16);
}
static __device__ __forceinline__ unsigned int pack2(unsigned short a, unsigned short b) {
    return (unsigned int)a | ((unsigned int)b << 16);
}

// ---- prep: tgt -> B-fragments; init mins; zero out ----
__global__ __launch_bounds__(BLK_P) void chamfer_prep(
    const float* __restrict__ tgt, uint4* __restrict__ fragT,
    unsigned int* __restrict__ mins, float* __restrict__ out)
{
    const int i = blockIdx.x * BLK_P + threadIdx.x;   // [0, B*NPTS)
    const unsigned short one = bf16h(1.0f);
    const float* tp = tgt + (size_t)i * 3;
    float px = tp[0], py = tp[1], pz = tp[2];
    float nx = -px, ny = -py, nz = -pz;
    float ht = 0.5f * fmaf(px, px, fmaf(py, py, pz * pz));
    unsigned short nxh = bf16h(nx), nxl = bf16h(nx - bf16tof(nxh));
    unsigned short nyh = bf16h(ny), nyl = bf16h(ny - bf16tof(nyh));
    unsigned short nzh = bf16h(nz), nzl = bf16h(nz - bf16tof(nzh));
    unsigned short hh = bf16h(ht),  hl = bf16h(ht - bf16tof(hh));
    fragT[2 * i + 0] = make_uint4(pack2(nxh, nxl), pack2(nxh, nyh),
                                  pack2(nyl, nyh), pack2(nzh, nzl));
    fragT[2 * i + 1] = make_uint4(pack2(nzh, one), pack2(one, hh),
                                  pack2(hl, one), 0u);   // slot 13 = 1 (bias)
    mins[i]        = 0x7f7f7f7fu;
    mins[SM_N + i] = 0x7f7f7f7fu;
    if (i < BATCH) out[i] = 0.0f;
}

__global__ __launch_bounds__(BLOCK, 2) void chamfer_nn(
    const float* __restrict__ src, const uint4* __restrict__ fragT,
    unsigned int* __restrict__ mins)
{
    __shared__ unsigned sht[2][DBR];   // per-half col-mins (biased u32), 8KB

    const int tid  = threadIdx.x;
    const int lane = tid & 63;
    const int w    = tid >> 6;         // wave 0..7
    const int half = lane >> 5;
    const int l31  = lane & 31;

    // ---- XCD-panel swizzle (bijective on [0,1024)) ----
    // panel = (b,ds) in [0,64); its 16 qb-siblings share lin&7 -> same XCD
    // -> 32KB fragment panel L2-resident (validated R10-R18).
    const int lin  = blockIdx.x;
    const int rest = lin >> 3;                        // [0,128)
    const int qb   = rest & 15;                       // [0,16)
    const int p    = ((rest >> 4) << 3) | (lin & 7);  // panel [0,64)
    const int b    = p & 7;
    const int ds   = p >> 3;                          // [0,8)

    // init col-min slots; one barrier before any wave's ds_min
    for (int j = tid; j < 2 * DBR; j += BLOCK) sht[0][j] = 0x7f7f7f7fu;

    // ---- build NAF A-fragments from src ----
    const unsigned short one = bf16h(1.0f);
    bf16x8 af[NAF];
#pragma unroll
    for (int g = 0; g < NAF; g++) {
        const int q = qb * QTILE + w * (32 * NAF) + g * 32 + l31;
        const float* qp = src + ((size_t)b * NPTS + q) * 3;
        float qx = qp[0], qy = qp[1], qz = qp[2];
        float hq = 0.5f * fmaf(qx, qx, fmaf(qy, qy, qz * qz));
        unsigned short xh = bf16h(qx), xl = bf16h(qx - bf16tof(xh));
        unsigned short yh = bf16h(qy), yl = bf16h(qy - bf16tof(yh));
        unsigned short zh = bf16h(qz), zl = bf16h(qz - bf16tof(zh));
        unsigned short qh = bf16h(hq), ql = bf16h(hq - bf16tof(qh));
        bf16x8 a;
        if (half == 0) {
            a[0] = (short)xh; a[1] = (short)xh; a[2] = (short)xl;
            a[3] = (short)yh; a[4] = (short)yh; a[5] = (short)yl;
            a[6] = (short)zh; a[7] = (short)zh;
        } else {
            a[0] = (short)zl; a[1] = (short)qh; a[2] = (short)ql;
            a[3] = (short)one; a[4] = (short)one;
            a[5] = (short)one;  // slot 13: pairs B's 1 -> +1.0 bias
            a[6] = 0; a[7] = 0;
        }
        af[g] = a;
    }

    unsigned rmn0[16], rmn1[16];
#pragma unroll
    for (int r = 0; r < 16; r++) { rmn0[r] = 0x7f7f7f7fu; rmn1[r] = 0x7f7f7f7fu; }
    const f32x16 zz = {};

    // per-lane B pointer (element 64*t + 2*l31 + half); coalesced, L2-hot.
    const uint4* gp = fragT + ((size_t)b * NPTS + (size_t)ds * DBR) * 2
                            + 2 * l31 + half;

    __syncthreads();   // sht init visible before any ds_min

    // register prefetch, 1-iteration distance (T14)
    uint4 c0 = gp[0], c1 = gp[64];
    for (int t = 0; t < NT; t += 2) {
        bf16x8 b0 = __builtin_bit_cast(bf16x8, c0);
        bf16x8 b1 = __builtin_bit_cast(bf16x8, c1);
        if (t + 2 < NT) {                   // issue next pair early
            c0 = gp[64 * (t + 2)];
            c1 = gp[64 * (t + 3)];
        }
        // ONE MFMA per unique tile x A-group (single-pass, R17-validated)
        f32x16 a00 = __builtin_amdgcn_mfma_f32_32x32x16_bf16(af[0], b0, zz, 0, 0, 0);
        f32x16 a01 = __builtin_amdgcn_mfma_f32_32x32x16_bf16(af[0], b1, zz, 0, 0, 0);
        f32x16 a10 = __builtin_amdgcn_mfma_f32_32x32x16_bf16(af[1], b0, zz, 0, 0, 0);
        f32x16 a11 = __builtin_amdgcn_mfma_f32_32x32x16_bf16(af[1], b1, zz, 0, 0, 0);
        // s2t: row-min accumulate (min over db points), u32 domain
#pragma unroll
        for (int r = 0; r < 16; r++) {
            rmn0[r] = umin3(rmn0[r], u(a00[r]), u(a01[r]));
            rmn1[r] = umin3(rmn1[r], u(a10[r]), u(a11[r]));
        }
        // t2s: per-half col-min into LDS (2 lanes/bank = free, m136)
        unsigned t0 = umin2(tree16u(a00), tree16u(a10));   // tile t
        unsigned t1 = umin2(tree16u(a01), tree16u(a11));   // tile t+1
        atomicMin(&sht[half][t * 32 + l31],       t0);
        atomicMin(&sht[half][(t + 1) * 32 + l31], t1);
    }

    // ---- s2t epilogue: fold cols 32->1 in-wave, global atomicMin ----
    unsigned int* M0 = mins + (size_t)b * NPTS;
    const int qbase = qb * QTILE + w * (32 * NAF);
#pragma unroll
    for (int r = 0; r < 16; r++) {
        unsigned a = rmn0[r], bv = rmn1[r];
#pragma unroll
        for (int off = 16; off > 0; off >>= 1) {
            a  = umin2(a,  (unsigned)__shfl_xor((int)a,  off, 64));
            bv = umin2(bv, (unsigned)__shfl_xor((int)bv, off, 64));
        }
        if (l31 == 0) {   // lanes 0 (half0 row) and 32 (half1 row)
            const int row = (r & 3) + 8 * (r >> 2) + 4 * half;
            atomicMin(&M0[qbase + row],      a);
            atomicMin(&M0[qbase + 32 + row], bv);
        }
    }

    // ---- t2s epilogue: merge halves, one global flush per block ----
    __syncthreads();   // all waves' ds_min complete
    unsigned int* M1 = mins + SM_N + (size_t)b * NPTS + (size_t)ds * DBR;
    for (int j = tid; j < DBR; j += BLOCK)
        atomicMin(&M1[j], umin2(sht[0][j], sht[1][j]));
}

// ---- final: un-bias, clamp, sum mins[2][B][NPTS], atomicAdd into out ----
__global__ __launch_bounds__(BLK_P) void chamfer_final(
    const unsigned int* __restrict__ mins, float* __restrict__ out)
{
    const int seg = blockIdx.x;   // 4 segments of 2048
    const int b   = blockIdx.y;
    const int tid = threadIdx.x;
    float acc = 0.0f;
#pragma unroll
    for (int k = 0; k < 8; k++) {
        const size_t i = (size_t)b * NPTS + seg * 2048 + k * BLK_P + tid;
        acc += fmaxf(__uint_as_float(mins[i]) - 1.0f, 0.0f)
             + fmaxf(__uint_as_float(mins[SM_N + i]) - 1.0f, 0.0f);
    }
    for (int off = 32; off > 0; off >>= 1) acc += __shfl_down(acc, off, 64);
    __shared__ float wsum[4];
    if ((tid & 63) == 0) wsum[tid >> 6] = acc;
    __syncthreads();
    if (tid == 0)   // stored values are (d/2 + 1): d = 2*(v-1)
        atomicAdd(&out[b],
                  (wsum[0] + wsum[1] + wsum[2] + wsum[3]) * (2.0f / (float)NPTS));
}

extern "C" void kernel_launch(void* const* d_in, const int* in_sizes, int n_in,
                              void* d_out, int out_size, void* d_ws, size_t ws_size,
                              hipStream_t stream) {
    const float* src = (const float*)d_in[0];  // [B, N, 3]
    const float* tgt = (const float*)d_in[1];  // [B, M, 3]
    float* out = (float*)d_out;                // [B]

    uint4* fragT        = (uint4*)d_ws;                     // 2 MB
    unsigned int* mins  = (unsigned int*)(fragT + FRAG_N);  // 512 KB

    chamfer_prep<<<BATCH * NPTS / BLK_P, BLK_P, 0, stream>>>(
        tgt, fragT, mins, out);
    chamfer_nn<<<NBLK, BLOCK, 0, stream>>>(src, fragT, mins);
    chamfer_final<<<dim3(4, BATCH), BLK_P, 0, stream>>>(mins, out);
}